// Round 6
// baseline (913.196 us; speedup 1.0000x reference)
//
#include <hip/hip_runtime.h>

#define NN 8192      // nodes
#define NE 262144    // edges per support (2^18)
#define BD 512       // batch*d_in feature rows
#define DE 64        // embedding dim

typedef __attribute__((ext_vector_type(8))) short short8;
typedef __attribute__((ext_vector_type(4))) short short4v;
typedef __attribute__((ext_vector_type(16))) float float16;

#define MFMA(a, b, c) __builtin_amdgcn_mfma_f32_32x32x16_bf16(a, b, c, 0, 0, 0)

static __device__ __forceinline__ unsigned short f2b(float x) {
  unsigned u = __float_as_uint(x);
  return (unsigned short)((u + 0x7fffu + ((u >> 16) & 1u)) >> 16);  // RNE
}
static __device__ __forceinline__ float b2f(unsigned short h) {
  return __uint_as_float(((unsigned)h) << 16);
}

// ---------------- transpose: Y0[n][f] = X[f][n]; Ysum = -Y0 ----------------
__global__ void k_transpose(const float* __restrict__ X, float* __restrict__ Y0,
                            float* __restrict__ Ysum) {
  __shared__ float t[32][33];
  int n0 = blockIdx.x * 32, f0 = blockIdx.y * 32;
  int tx = threadIdx.x, ty = threadIdx.y;
#pragma unroll
  for (int yy = 0; yy < 4; yy++)
    t[ty + 8 * yy][tx] = X[(size_t)(f0 + ty + 8 * yy) * NN + n0 + tx];
  __syncthreads();
#pragma unroll
  for (int yy = 0; yy < 4; yy++) {
    float v = t[tx][ty + 8 * yy];
    size_t o = (size_t)(n0 + ty + 8 * yy) * BD + f0 + tx;
    Y0[o] = v;
    Ysum[o] = -v;
  }
}

// ---------------- cast: Y0bT[f][n] = bf16(X[f][n])  (X already [f][n]) ----------------
__global__ void k_cast(const float* __restrict__ X, unsigned short* __restrict__ Y0bT) {
  size_t t = (size_t)(blockIdx.x * 256 + threadIdx.x) * 8;
  float4 a = *(const float4*)(X + t);
  float4 b = *(const float4*)(X + t + 4);
  short8 v;
  v[0] = (short)f2b(a.x); v[1] = (short)f2b(a.y);
  v[2] = (short)f2b(a.z); v[3] = (short)f2b(a.w);
  v[4] = (short)f2b(b.x); v[5] = (short)f2b(b.y);
  v[6] = (short)f2b(b.z); v[7] = (short)f2b(b.w);
  *(short8*)(Y0bT + t) = v;
}

// ---------------- Z split: Z ~= Zh + Zl (bf16 pair) ----------------
__global__ void k_zsplit(const float* __restrict__ Z, unsigned short* __restrict__ Zh,
                         unsigned short* __restrict__ Zl) {
  size_t t = (size_t)(blockIdx.x * 256 + threadIdx.x) * 4;
  float4 a = *(const float4*)(Z + t);
  float f[4] = {a.x, a.y, a.z, a.w};
  short4v hv, lv;
#pragma unroll
  for (int i = 0; i < 4; i++) {
    unsigned short hh = f2b(f[i]);
    hv[i] = (short)hh;
    lv[i] = (short)f2b(f[i] - b2f(hh));
  }
  *(short4v*)(Zh + t) = hv;
  *(short4v*)(Zl + t) = lv;
}

// ---------------- colsum: ssum[j] = sum_i exp(relu(Z_i . Z_j))  (MFMA) ----------------
__global__ __launch_bounds__(256) void k_colsum(const unsigned short* __restrict__ Zh,
                                                const unsigned short* __restrict__ Zl,
                                                float* __restrict__ ssum) {
  int jt = blockIdx.x;     // 128 j-tiles of 64
  int chunk = blockIdx.y;  // 4 i-chunks of 2048
  int tid = threadIdx.x;
  int w = tid >> 6, lane = tid & 63, li = lane & 31, h = lane >> 5;
  int jb = jt * 64 + (w & 1) * 32 + li;
  short8 bjh[4], bjl[4];
#pragma unroll
  for (int ks = 0; ks < 4; ks++) {
    bjh[ks] = *(const short8*)(Zh + (size_t)jb * DE + ks * 16 + 8 * h);
    bjl[ks] = *(const short8*)(Zl + (size_t)jb * DE + ks * 16 + 8 * h);
  }
  float csum = 0.f;
  for (int it = 0; it < 32; it++) {
    int ib = chunk * 2048 + (w >> 1) * 32 + it * 64 + li;
    short8 aih[4], ail[4];
#pragma unroll
    for (int ks = 0; ks < 4; ks++) {
      aih[ks] = *(const short8*)(Zh + (size_t)ib * DE + ks * 16 + 8 * h);
      ail[ks] = *(const short8*)(Zl + (size_t)ib * DE + ks * 16 + 8 * h);
    }
    float16 s;
#pragma unroll
    for (int r = 0; r < 16; r++) s[r] = 0.f;
#pragma unroll
    for (int ks = 0; ks < 4; ks++) {
      s = MFMA(aih[ks], bjh[ks], s);
      s = MFMA(aih[ks], bjl[ks], s);
      s = MFMA(ail[ks], bjh[ks], s);
    }
#pragma unroll
    for (int r = 0; r < 16; r++)
      csum += __expf(fminf(fmaxf(s[r], 0.f), 80.f));
  }
  csum += __shfl_xor(csum, 32);
  if (lane < 32) atomicAdd(ssum + jb, csum);
}

__global__ void k_inv(const float* __restrict__ ssum, float* __restrict__ invs) {
  int i = blockIdx.x * 256 + threadIdx.x;
  invs[i] = 1.0f / ssum[i];
}

// ---------------- CSR build ----------------
__global__ void k_hist(const int* __restrict__ erow, int* __restrict__ cnt) {
  int t = blockIdx.x * 256 + threadIdx.x;  // t over 2*NE
  int k = t >> 18;
  atomicAdd(cnt + k * NN + erow[t], 1);
}

#define RPS 8208  // rowptr stride per support (padded)
__global__ __launch_bounds__(256) void k_scan(const int* __restrict__ cnt,
                                              int* __restrict__ rowptr,
                                              int* __restrict__ fill) {
  int k = blockIdx.x;
  const int* c = cnt + k * NN;
  int* rp = rowptr + k * RPS;
  int* fl = fill + k * NN;
  __shared__ int part[256];
  int t = threadIdx.x;
  int local[32];
  int s = 0;
#pragma unroll
  for (int i = 0; i < 32; i++) { local[i] = c[t * 32 + i]; s += local[i]; }
  part[t] = s;
  __syncthreads();
  for (int off = 1; off < 256; off <<= 1) {
    int v = (t >= off) ? part[t - off] : 0;
    __syncthreads();
    part[t] += v;
    __syncthreads();
  }
  int run = (t == 0) ? 0 : part[t - 1];
#pragma unroll
  for (int i = 0; i < 32; i++) {
    rp[t * 32 + i] = run;
    fl[t * 32 + i] = run;
    run += local[i];
  }
  if (t == 255) rp[NN] = run;
}

__global__ void k_scatter(const int* __restrict__ erow, const int* __restrict__ ecol,
                          const float* __restrict__ ew, int* __restrict__ fill,
                          int* __restrict__ ecol_s, float* __restrict__ ew_s) {
  int t = blockIdx.x * 256 + threadIdx.x;  // t over 2*NE
  int k = t >> 18;
  int r = erow[t];
  int pos = atomicAdd(fill + k * NN + r, 1);
  ecol_s[(size_t)k * NE + pos] = ecol[t];
  ew_s[(size_t)k * NE + pos] = ew[t];
}

// ---------------- CSR SpMM (f32 gather): one wave per row, no atomics ----------------
__global__ __launch_bounds__(256) void k_csr(const int* __restrict__ rowptr,
                                             const int* __restrict__ cols,
                                             const float* __restrict__ w,
                                             const float* __restrict__ src,
                                             float* __restrict__ dst,
                                             const float* __restrict__ extra,
                                             float scale) {
  int wid = threadIdx.x >> 6;
  int lane = threadIdx.x & 63;
  int row = blockIdx.x * 4 + wid;
  int start = rowptr[row], end = rowptr[row + 1];
  float a0x = 0.f, a0y = 0.f, a0z = 0.f, a0w = 0.f;
  float a1x = 0.f, a1y = 0.f, a1z = 0.f, a1w = 0.f;
  for (int e = start; e < end; e++) {
    int c = __builtin_amdgcn_readfirstlane(cols[e]);
    float wv = w[e];
    const float4* s = (const float4*)(src + (size_t)c * BD);
    float4 v0 = s[lane], v1 = s[lane + 64];
    a0x += wv * v0.x; a0y += wv * v0.y; a0z += wv * v0.z; a0w += wv * v0.w;
    a1x += wv * v1.x; a1y += wv * v1.y; a1z += wv * v1.z; a1w += wv * v1.w;
  }
  float4* d = (float4*)(dst + (size_t)row * BD);
  if (extra) {
    const float4* ex = (const float4*)(extra + (size_t)row * BD);
    float4 e0 = ex[lane], e1 = ex[lane + 64];
    float4 d0 = d[lane], d1 = d[lane + 64];
    d0.x += scale * a0x + e0.x; d0.y += scale * a0y + e0.y;
    d0.z += scale * a0z + e0.z; d0.w += scale * a0w + e0.w;
    d1.x += scale * a1x + e1.x; d1.y += scale * a1y + e1.y;
    d1.z += scale * a1z + e1.z; d1.w += scale * a1w + e1.w;
    d[lane] = d0; d[lane + 64] = d1;
  } else {
    float4 d0 = {a0x, a0y, a0z, a0w};
    float4 d1 = {a1x, a1y, a1z, a1w};
    d[lane] = d0; d[lane + 64] = d1;
  }
}

// ---------------- fused adaptive-adjacency MFMA GEMM, barrier-free main loop ----------------
// Ysum[i, f] += sum_j exp(relu(Z_i.Z_j))*invs[j] * Y0[j, f]
// Swapped S: S_T[j][i] = mfma(A=Zj, B=Zi) -> lane holds col i, rows j.
// P packed via cvt_pk + permlane32_swap -> PV A-frags fully in-register.
// Each wave owns a disjoint j-subset; epilogue reduces the 4 partial accs in LDS
// (R4/R5 bug: non-atomic += from 4 waves to the same (i,f) tile raced).
__global__ __launch_bounds__(256, 2) void k2(const unsigned short* __restrict__ Zh,
                                             const unsigned short* __restrict__ Zl,
                                             const unsigned short* __restrict__ Y0bT,
                                             const float* __restrict__ invs,
                                             float* __restrict__ Ysum) {
  __shared__ float red[4][32][33];
  int bid = blockIdx.x;       // 512 blocks
  int fhalf = bid & 1;        // XCD-parity: each XCD sees one f-half (L2-fit)
  int itile = bid >> 1;       // 0..255
  int i0 = itile * 32;
  int f0 = fhalf * 256;
  int tid = threadIdx.x;
  int w = tid >> 6, lane = tid & 63, li = lane & 31, h = lane >> 5;

  // hoist B-operand for S: Zi rows i0+li
  short8 bih[4], bil[4];
#pragma unroll
  for (int ks = 0; ks < 4; ks++) {
    bih[ks] = *(const short8*)(Zh + (size_t)(i0 + li) * DE + ks * 16 + 8 * h);
    bil[ks] = *(const short8*)(Zl + (size_t)(i0 + li) * DE + ks * 16 + 8 * h);
  }
  float16 acc[8];
#pragma unroll
  for (int ft = 0; ft < 8; ft++)
#pragma unroll
    for (int r = 0; r < 16; r++) acc[ft][r] = 0.f;

#pragma unroll 1
  for (int t = 0; t < 64; t++) {
    int jb = t * 128 + w * 32;  // this wave's 32-j chunk
    short8 ajh[4], ajl[4];
#pragma unroll
    for (int ks = 0; ks < 4; ks++) {
      ajh[ks] = *(const short8*)(Zh + (size_t)(jb + li) * DE + ks * 16 + 8 * h);
      ajl[ks] = *(const short8*)(Zl + (size_t)(jb + li) * DE + ks * 16 + 8 * h);
    }
    float16 s;
#pragma unroll
    for (int r = 0; r < 16; r++) s[r] = 0.f;
#pragma unroll
    for (int ks = 0; ks < 4; ks++) {
      s = MFMA(ajh[ks], bih[ks], s);  // hi*hi
      s = MFMA(ajh[ks], bil[ks], s);  // hi_j*lo_i
      s = MFMA(ajl[ks], bih[ks], s);  // lo_j*hi_i
    }
    // p = exp(relu(S))*invs[j], packed bf16 pairs along j
    unsigned wds[8];
#pragma unroll
    for (int q = 0; q < 8; q++) {
      int r0 = q * 2;
      int jl0 = 2 * (q & 1) + 8 * (q >> 1) + 4 * h;  // j_rel of r0
      float iv0 = invs[jb + jl0];
      float iv1 = invs[jb + jl0 + 1];
      float p0 = __expf(fminf(fmaxf(s[r0], 0.f), 80.f)) * iv0;
      float p1 = __expf(fminf(fmaxf(s[r0 + 1], 0.f), 80.f)) * iv1;
      asm("v_cvt_pk_bf16_f32 %0, %1, %2" : "=v"(wds[q]) : "v"(p0), "v"(p1));
    }
    // PV: 2 k-steps of 16 j; A-frag via permlane32_swap (both outputs used)
#pragma unroll
    for (int ks2 = 0; ks2 < 2; ks2++) {
      unsigned A0 = wds[ks2 * 4 + 0], A1 = wds[ks2 * 4 + 1];
      unsigned A2 = wds[ks2 * 4 + 2], A3 = wds[ks2 * 4 + 3];
      asm("v_permlane32_swap_b32 %0, %1" : "+v"(A0), "+v"(A2));
      asm("v_permlane32_swap_b32 %0, %1" : "+v"(A1), "+v"(A3));
      union { unsigned u[4]; short8 s8; } fu;
      fu.u[0] = A0; fu.u[1] = A1; fu.u[2] = A2; fu.u[3] = A3;
#pragma unroll
      for (int ft = 0; ft < 8; ft++) {
        const unsigned short* bp =
            Y0bT + (size_t)(f0 + ft * 32 + li) * NN + jb + ks2 * 16 + 8 * h;
        short8 B = *(const short8*)bp;
        acc[ft] = MFMA(fu.s8, B, acc[ft]);
      }
    }
  }
  // epilogue: cross-wave reduction (4 waves hold partials over disjoint j-subsets)
#pragma unroll 1
  for (int ft = 0; ft < 8; ft++) {
    __syncthreads();  // previous round's reads done (no-op at ft=0)
#pragma unroll
    for (int r = 0; r < 16; r++) {
      int ir = (r & 3) + 8 * (r >> 2) + 4 * h;
      red[w][ir][li] = acc[ft][r];
    }
    __syncthreads();
#pragma unroll
    for (int q = 0; q < 4; q++) {
      int e = q * 256 + tid;
      int row = e >> 5, col = e & 31;
      float sv = red[0][row][col] + red[1][row][col] +
                 red[2][row][col] + red[3][row][col];
      Ysum[(size_t)(i0 + row) * BD + f0 + ft * 32 + col] += sv;
    }
  }
}

// ---------------- out[b,n,o] = sum_d Ysum[n, b*32+d] * W[d,o] ----------------
__global__ void k3(const float* __restrict__ Ysum, const float* __restrict__ W,
                   float* __restrict__ out) {
  __shared__ float yt[32][68];  // [d][n]
  __shared__ float wt[32][68];  // [d][o]
  int n0 = blockIdx.x * 64;
  int b = blockIdx.y;
  int tid = threadIdx.x;
#pragma unroll
  for (int q = 0; q < 2; q++) {
    int flat = (q * 256 + tid) * 4;
    int r = flat >> 5, c = flat & 31;
    float4 a = *(const float4*)(Ysum + (size_t)(n0 + r) * BD + b * 32 + c);
    yt[c + 0][r] = a.x; yt[c + 1][r] = a.y; yt[c + 2][r] = a.z; yt[c + 3][r] = a.w;
    int rd = flat >> 6, co = flat & 63;
    *(float4*)&wt[rd][co] = *(const float4*)(W + rd * 64 + co);
  }
  __syncthreads();
  int tx = tid & 15, ty = tid >> 4;
  float acc[4][4];
#pragma unroll
  for (int a = 0; a < 4; a++)
#pragma unroll
    for (int bq = 0; bq < 4; bq++) acc[a][bq] = 0.f;
#pragma unroll
  for (int d = 0; d < 32; d++) {
    float4 a = *(const float4*)&yt[d][ty * 4];
    float4 w4 = *(const float4*)&wt[d][tx * 4];
    float av[4] = {a.x, a.y, a.z, a.w}, wv[4] = {w4.x, w4.y, w4.z, w4.w};
#pragma unroll
    for (int nn = 0; nn < 4; nn++)
#pragma unroll
      for (int oo = 0; oo < 4; oo++) acc[nn][oo] += av[nn] * wv[oo];
  }
#pragma unroll
  for (int nn = 0; nn < 4; nn++) {
    float4 v = {acc[nn][0], acc[nn][1], acc[nn][2], acc[nn][3]};
    *(float4*)(out + (size_t)b * NN * 64 + (size_t)(n0 + ty * 4 + nn) * 64 + tx * 4) = v;
  }
}

extern "C" void kernel_launch(void* const* d_in, const int* in_sizes, int n_in,
                              void* d_out, int out_size, void* d_ws, size_t ws_size,
                              hipStream_t stream) {
  const int* erow = (const int*)d_in[0];
  const int* ecol = (const int*)d_in[1];
  const float* ew = (const float*)d_in[2];
  const float* X = (const float*)d_in[3];
  const float* Z = (const float*)d_in[4];
  const float* W = (const float*)d_in[5];
  float* out = (float*)d_out;

  char* p = (char*)d_ws;
  float* Y0 = (float*)p;                     p += (size_t)NN * BD * 4;  // 16 MB
  float* Ysum = (float*)p;                   p += (size_t)NN * BD * 4;  // 16 MB
  float* Y1 = (float*)p;                     p += (size_t)NN * BD * 4;  // 16 MB
  unsigned short* Y0bT = (unsigned short*)p; p += (size_t)BD * NN * 2;  // 8 MB
  unsigned short* Zh = (unsigned short*)p;   p += (size_t)NN * DE * 2;  // 1 MB
  unsigned short* Zl = (unsigned short*)p;   p += (size_t)NN * DE * 2;  // 1 MB
  float* ssum = (float*)p;                   p += NN * 4;
  float* invs = (float*)p;                   p += NN * 4;
  int* cnt = (int*)p;                        p += 2 * NN * 4;
  int* rowptr = (int*)p;                     p += 2 * RPS * 4;
  int* fill = (int*)p;                       p += 2 * NN * 4;
  int* ecol_s = (int*)p;                     p += (size_t)2 * NE * 4;
  float* ew_s = (float*)p;                   p += (size_t)2 * NE * 4;

  k_transpose<<<dim3(NN / 32, BD / 32), dim3(32, 8), 0, stream>>>(X, Y0, Ysum);
  k_zsplit<<<(NN * DE / 4) / 256, 256, 0, stream>>>(Z, Zh, Zl);
  hipMemsetAsync(ssum, 0, NN * sizeof(float), stream);
  hipMemsetAsync(cnt, 0, 2 * NN * sizeof(int), stream);
  k_hist<<<2 * NE / 256, 256, 0, stream>>>(erow, cnt);
  k_scan<<<2, 256, 0, stream>>>(cnt, rowptr, fill);
  k_scatter<<<2 * NE / 256, 256, 0, stream>>>(erow, ecol, ew, fill, ecol_s, ew_s);
  k_colsum<<<dim3(128, 4), 256, 0, stream>>>(Zh, Zl, ssum);
  k_inv<<<NN / 256, 256, 0, stream>>>(ssum, invs);
  for (int k = 0; k < 2; k++) {
    const int* rp = rowptr + k * RPS;
    const int* cs = ecol_s + (size_t)k * NE;
    const float* ws = ew_s + (size_t)k * NE;
    k_csr<<<NN / 4, 256, 0, stream>>>(rp, cs, ws, Y0, Y1, nullptr, 1.0f);
    k_csr<<<NN / 4, 256, 0, stream>>>(rp, cs, ws, Y1, Ysum, Y1, 2.0f);
  }
  k_cast<<<(NN * BD / 8) / 256, 256, 0, stream>>>(X, Y0bT);
  k2<<<512, 256, 0, stream>>>(Zh, Zl, Y0bT, invs, Ysum);
  k3<<<dim3(NN / 64, 16), 256, 0, stream>>>(Ysum, W, out);
}

// Round 7
// 804.200 us; speedup vs baseline: 1.1355x; 1.1355x over previous
//
#include <hip/hip_runtime.h>

#define NN 8192      // nodes
#define NE 262144    // edges per support (2^18)
#define BD 512       // batch*d_in feature rows
#define DE 64        // embedding dim

typedef __attribute__((ext_vector_type(8))) short short8;
typedef __attribute__((ext_vector_type(4))) short short4v;
typedef __attribute__((ext_vector_type(16))) float float16;

#define MFMA(a, b, c) __builtin_amdgcn_mfma_f32_32x32x16_bf16(a, b, c, 0, 0, 0)

static __device__ __forceinline__ unsigned short f2b(float x) {
  unsigned u = __float_as_uint(x);
  return (unsigned short)((u + 0x7fffu + ((u >> 16) & 1u)) >> 16);  // RNE
}
static __device__ __forceinline__ float b2f(unsigned short h) {
  return __uint_as_float(((unsigned)h) << 16);
}

// ---------------- transpose: Y0[n][f] = X[f][n]; Ysum = -Y0 ----------------
__global__ void k_transpose(const float* __restrict__ X, float* __restrict__ Y0,
                            float* __restrict__ Ysum) {
  __shared__ float t[32][33];
  int n0 = blockIdx.x * 32, f0 = blockIdx.y * 32;
  int tx = threadIdx.x, ty = threadIdx.y;
#pragma unroll
  for (int yy = 0; yy < 4; yy++)
    t[ty + 8 * yy][tx] = X[(size_t)(f0 + ty + 8 * yy) * NN + n0 + tx];
  __syncthreads();
#pragma unroll
  for (int yy = 0; yy < 4; yy++) {
    float v = t[tx][ty + 8 * yy];
    size_t o = (size_t)(n0 + ty + 8 * yy) * BD + f0 + tx;
    Y0[o] = v;
    Ysum[o] = -v;
  }
}

// ------- blocked cast: Y0bB[n>>5][f][n&31] = bf16(X[f][n])  (32-n tiles) -------
__global__ void k_castB(const float* __restrict__ X, unsigned short* __restrict__ Y0bB) {
  int t = blockIdx.x * 256 + threadIdx.x;
  int f = t >> 10;                 // 8192/8 = 1024 chunks per f-row
  int n0 = (t & 1023) * 8;
  const float* src = X + (size_t)f * NN + n0;
  float4 a = *(const float4*)(src);
  float4 b = *(const float4*)(src + 4);
  short8 v;
  v[0] = (short)f2b(a.x); v[1] = (short)f2b(a.y);
  v[2] = (short)f2b(a.z); v[3] = (short)f2b(a.w);
  v[4] = (short)f2b(b.x); v[5] = (short)f2b(b.y);
  v[6] = (short)f2b(b.z); v[7] = (short)f2b(b.w);
  size_t o = ((size_t)(n0 >> 5) * BD + f) * 32 + (n0 & 31);
  *(short8*)(Y0bB + o) = v;
}

// ---------------- Z split: Z ~= Zh + Zl (bf16 pair) ----------------
__global__ void k_zsplit(const float* __restrict__ Z, unsigned short* __restrict__ Zh,
                         unsigned short* __restrict__ Zl) {
  size_t t = (size_t)(blockIdx.x * 256 + threadIdx.x) * 4;
  float4 a = *(const float4*)(Z + t);
  float f[4] = {a.x, a.y, a.z, a.w};
  short4v hv, lv;
#pragma unroll
  for (int i = 0; i < 4; i++) {
    unsigned short hh = f2b(f[i]);
    hv[i] = (short)hh;
    lv[i] = (short)f2b(f[i] - b2f(hh));
  }
  *(short4v*)(Zh + t) = hv;
  *(short4v*)(Zl + t) = lv;
}

// ---------------- colsum: ssum[j] = sum_i exp(relu(Z_i . Z_j))  (MFMA) ----------------
__global__ __launch_bounds__(256) void k_colsum(const unsigned short* __restrict__ Zh,
                                                const unsigned short* __restrict__ Zl,
                                                float* __restrict__ ssum) {
  int jt = blockIdx.x;     // 128 j-tiles of 64
  int chunk = blockIdx.y;  // 4 i-chunks of 2048
  int tid = threadIdx.x;
  int w = tid >> 6, lane = tid & 63, li = lane & 31, h = lane >> 5;
  int jb = jt * 64 + (w & 1) * 32 + li;
  short8 bjh[4], bjl[4];
#pragma unroll
  for (int ks = 0; ks < 4; ks++) {
    bjh[ks] = *(const short8*)(Zh + (size_t)jb * DE + ks * 16 + 8 * h);
    bjl[ks] = *(const short8*)(Zl + (size_t)jb * DE + ks * 16 + 8 * h);
  }
  float csum = 0.f;
  for (int it = 0; it < 32; it++) {
    int ib = chunk * 2048 + (w >> 1) * 32 + it * 64 + li;
    short8 aih[4], ail[4];
#pragma unroll
    for (int ks = 0; ks < 4; ks++) {
      aih[ks] = *(const short8*)(Zh + (size_t)ib * DE + ks * 16 + 8 * h);
      ail[ks] = *(const short8*)(Zl + (size_t)ib * DE + ks * 16 + 8 * h);
    }
    float16 s;
#pragma unroll
    for (int r = 0; r < 16; r++) s[r] = 0.f;
#pragma unroll
    for (int ks = 0; ks < 4; ks++) {
      s = MFMA(aih[ks], bjh[ks], s);
      s = MFMA(aih[ks], bjl[ks], s);
      s = MFMA(ail[ks], bjh[ks], s);
    }
#pragma unroll
    for (int r = 0; r < 16; r++)
      csum += __expf(fminf(fmaxf(s[r], 0.f), 80.f));
  }
  csum += __shfl_xor(csum, 32);
  if (lane < 32) atomicAdd(ssum + jb, csum);
}

__global__ void k_inv(const float* __restrict__ ssum, float* __restrict__ invs) {
  int i = blockIdx.x * 256 + threadIdx.x;
  invs[i] = 1.0f / ssum[i];
}

// ---------------- CSR build ----------------
__global__ void k_hist(const int* __restrict__ erow, int* __restrict__ cnt) {
  int t = blockIdx.x * 256 + threadIdx.x;  // t over 2*NE
  int k = t >> 18;
  atomicAdd(cnt + k * NN + erow[t], 1);
}

#define RPS 8208  // rowptr stride per support (padded)
__global__ __launch_bounds__(256) void k_scan(const int* __restrict__ cnt,
                                              int* __restrict__ rowptr,
                                              int* __restrict__ fill) {
  int k = blockIdx.x;
  const int* c = cnt + k * NN;
  int* rp = rowptr + k * RPS;
  int* fl = fill + k * NN;
  __shared__ int part[256];
  int t = threadIdx.x;
  int local[32];
  int s = 0;
#pragma unroll
  for (int i = 0; i < 32; i++) { local[i] = c[t * 32 + i]; s += local[i]; }
  part[t] = s;
  __syncthreads();
  for (int off = 1; off < 256; off <<= 1) {
    int v = (t >= off) ? part[t - off] : 0;
    __syncthreads();
    part[t] += v;
    __syncthreads();
  }
  int run = (t == 0) ? 0 : part[t - 1];
#pragma unroll
  for (int i = 0; i < 32; i++) {
    rp[t * 32 + i] = run;
    fl[t * 32 + i] = run;
    run += local[i];
  }
  if (t == 255) rp[NN] = run;
}

__global__ void k_scatter(const int* __restrict__ erow, const int* __restrict__ ecol,
                          const float* __restrict__ ew, int* __restrict__ fill,
                          int* __restrict__ ecol_s, float* __restrict__ ew_s) {
  int t = blockIdx.x * 256 + threadIdx.x;  // t over 2*NE
  int k = t >> 18;
  int r = erow[t];
  int pos = atomicAdd(fill + k * NN + r, 1);
  ecol_s[(size_t)k * NE + pos] = ecol[t];
  ew_s[(size_t)k * NE + pos] = ew[t];
}

// ---------------- CSR SpMM (f32 gather): one wave per row, no atomics ----------------
__global__ __launch_bounds__(256) void k_csr(const int* __restrict__ rowptr,
                                             const int* __restrict__ cols,
                                             const float* __restrict__ w,
                                             const float* __restrict__ src,
                                             float* __restrict__ dst,
                                             const float* __restrict__ extra,
                                             float scale) {
  int wid = threadIdx.x >> 6;
  int lane = threadIdx.x & 63;
  int row = blockIdx.x * 4 + wid;
  int start = rowptr[row], end = rowptr[row + 1];
  float a0x = 0.f, a0y = 0.f, a0z = 0.f, a0w = 0.f;
  float a1x = 0.f, a1y = 0.f, a1z = 0.f, a1w = 0.f;
  for (int e = start; e < end; e++) {
    int c = __builtin_amdgcn_readfirstlane(cols[e]);
    float wv = w[e];
    const float4* s = (const float4*)(src + (size_t)c * BD);
    float4 v0 = s[lane], v1 = s[lane + 64];
    a0x += wv * v0.x; a0y += wv * v0.y; a0z += wv * v0.z; a0w += wv * v0.w;
    a1x += wv * v1.x; a1y += wv * v1.y; a1z += wv * v1.z; a1w += wv * v1.w;
  }
  float4* d = (float4*)(dst + (size_t)row * BD);
  if (extra) {
    const float4* ex = (const float4*)(extra + (size_t)row * BD);
    float4 e0 = ex[lane], e1 = ex[lane + 64];
    float4 d0 = d[lane], d1 = d[lane + 64];
    d0.x += scale * a0x + e0.x; d0.y += scale * a0y + e0.y;
    d0.z += scale * a0z + e0.z; d0.w += scale * a0w + e0.w;
    d1.x += scale * a1x + e1.x; d1.y += scale * a1y + e1.y;
    d1.z += scale * a1z + e1.z; d1.w += scale * a1w + e1.w;
    d[lane] = d0; d[lane + 64] = d1;
  } else {
    float4 d0 = {a0x, a0y, a0z, a0w};
    float4 d1 = {a1x, a1y, a1z, a1w};
    d[lane] = d0; d[lane + 64] = d1;
  }
}

// ---------------- fused adaptive-adjacency MFMA GEMM ----------------
// Ysum[i, f] += sum_j exp(relu(Z_i.Z_j))*invs[j] * Y0[j, f]
// Block: 64 i x 128 f (f-quarter = bid&3 -> XCD-local 2MB B set).
// Wave: own 32-j chunk; S_T[j][i] = mfma(Zj, Zi) for 2 i-frags; P via
// cvt_pk+permlane; PV B-frag (blocked Y0bB, consecutive lines) feeds BOTH
// i-frags. Epilogue: cross-wave LDS reduction (j-split partials).
__global__ __launch_bounds__(256, 2) void k2(const unsigned short* __restrict__ Zh,
                                             const unsigned short* __restrict__ Zl,
                                             const unsigned short* __restrict__ Y0bB,
                                             const float* __restrict__ invs,
                                             float* __restrict__ Ysum) {
  __shared__ float red[4][32][33];
  int bid = blockIdx.x;        // 512 blocks
  int fq = bid & 3;            // f-quarter: XCD x serves fq = x&3 only
  int itile = bid >> 2;        // 0..127
  int i0 = itile * 64;
  int f0 = fq * 128;
  int phase = itile & 63;      // stagger j-loop start
  int tid = threadIdx.x;
  int w = tid >> 6, lane = tid & 63, li = lane & 31, h = lane >> 5;

  // hoist B-operand for S: Zi rows (2 i-frags, hi/lo)
  short8 bih[2][4], bil[2][4];
#pragma unroll
  for (int ifr = 0; ifr < 2; ifr++)
#pragma unroll
    for (int ks = 0; ks < 4; ks++) {
      bih[ifr][ks] = *(const short8*)(Zh + (size_t)(i0 + ifr * 32 + li) * DE + ks * 16 + 8 * h);
      bil[ifr][ks] = *(const short8*)(Zl + (size_t)(i0 + ifr * 32 + li) * DE + ks * 16 + 8 * h);
    }
  float16 acc[4][2];
#pragma unroll
  for (int ft = 0; ft < 4; ft++)
#pragma unroll
    for (int ifr = 0; ifr < 2; ifr++)
#pragma unroll
      for (int r = 0; r < 16; r++) acc[ft][ifr][r] = 0.f;

#pragma unroll 1
  for (int tt = 0; tt < 64; tt++) {
    int t = (tt + phase) & 63;
    int jb = t * 128 + w * 32;   // this wave's 32-j chunk
    int jt = t * 4 + w;          // Y0bB tile index
    float16 s0, s1;
#pragma unroll
    for (int r = 0; r < 16; r++) { s0[r] = 0.f; s1[r] = 0.f; }
#pragma unroll
    for (int ks = 0; ks < 4; ks++) {
      short8 ajh = *(const short8*)(Zh + (size_t)(jb + li) * DE + ks * 16 + 8 * h);
      short8 ajl = *(const short8*)(Zl + (size_t)(jb + li) * DE + ks * 16 + 8 * h);
      s0 = MFMA(ajh, bih[0][ks], s0);
      s0 = MFMA(ajh, bil[0][ks], s0);
      s0 = MFMA(ajl, bih[0][ks], s0);
      s1 = MFMA(ajh, bih[1][ks], s1);
      s1 = MFMA(ajh, bil[1][ks], s1);
      s1 = MFMA(ajl, bih[1][ks], s1);
    }
    // p = exp(relu(S))*invs[j], packed bf16 pairs along j (per i-frag)
    unsigned wds0[8], wds1[8];
#pragma unroll
    for (int q = 0; q < 8; q++) {
      int r0 = q * 2;
      int jl0 = 2 * (q & 1) + 8 * (q >> 1) + 4 * h;  // j_rel of r0
      float iv0 = invs[jb + jl0];
      float iv1 = invs[jb + jl0 + 1];
      float p0 = __expf(fminf(fmaxf(s0[r0], 0.f), 80.f)) * iv0;
      float p1 = __expf(fminf(fmaxf(s0[r0 + 1], 0.f), 80.f)) * iv1;
      asm("v_cvt_pk_bf16_f32 %0, %1, %2" : "=v"(wds0[q]) : "v"(p0), "v"(p1));
      float p2 = __expf(fminf(fmaxf(s1[r0], 0.f), 80.f)) * iv0;
      float p3 = __expf(fminf(fmaxf(s1[r0 + 1], 0.f), 80.f)) * iv1;
      asm("v_cvt_pk_bf16_f32 %0, %1, %2" : "=v"(wds1[q]) : "v"(p2), "v"(p3));
    }
    // PV: 2 k-steps of 16 j; A-frags via permlane32_swap; one B feeds both i-frags
#pragma unroll
    for (int ks2 = 0; ks2 < 2; ks2++) {
      unsigned A0 = wds0[ks2 * 4 + 0], A1 = wds0[ks2 * 4 + 1];
      unsigned A2 = wds0[ks2 * 4 + 2], A3 = wds0[ks2 * 4 + 3];
      asm("v_permlane32_swap_b32 %0, %1" : "+v"(A0), "+v"(A2));
      asm("v_permlane32_swap_b32 %0, %1" : "+v"(A1), "+v"(A3));
      union { unsigned u[4]; short8 s8; } fu0;
      fu0.u[0] = A0; fu0.u[1] = A1; fu0.u[2] = A2; fu0.u[3] = A3;
      unsigned B0 = wds1[ks2 * 4 + 0], B1 = wds1[ks2 * 4 + 1];
      unsigned B2 = wds1[ks2 * 4 + 2], B3 = wds1[ks2 * 4 + 3];
      asm("v_permlane32_swap_b32 %0, %1" : "+v"(B0), "+v"(B2));
      asm("v_permlane32_swap_b32 %0, %1" : "+v"(B1), "+v"(B3));
      union { unsigned u[4]; short8 s8; } fu1;
      fu1.u[0] = B0; fu1.u[1] = B1; fu1.u[2] = B2; fu1.u[3] = B3;
#pragma unroll
      for (int ft = 0; ft < 4; ft++) {
        const unsigned short* bp =
            Y0bB + ((size_t)jt * BD + f0 + ft * 32 + li) * 32 + ks2 * 16 + 8 * h;
        short8 B = *(const short8*)bp;
        acc[ft][0] = MFMA(fu0.s8, B, acc[ft][0]);
        acc[ft][1] = MFMA(fu1.s8, B, acc[ft][1]);
      }
    }
  }
  // epilogue: cross-wave reduction (4 waves hold partials over disjoint j-subsets)
#pragma unroll 1
  for (int fi = 0; fi < 8; fi++) {
    int ft = fi >> 1, ifr = fi & 1;
    __syncthreads();
#pragma unroll
    for (int r = 0; r < 16; r++) {
      int ir = (r & 3) + 8 * (r >> 2) + 4 * h;
      red[w][ir][li] = acc[ft][ifr][r];
    }
    __syncthreads();
#pragma unroll
    for (int q = 0; q < 4; q++) {
      int e = q * 256 + tid;
      int row = e >> 5, col = e & 31;
      float sv = red[0][row][col] + red[1][row][col] +
                 red[2][row][col] + red[3][row][col];
      Ysum[(size_t)(i0 + ifr * 32 + row) * BD + f0 + ft * 32 + col] += sv;
    }
  }
}

// ---------------- out[b,n,o] = sum_d Ysum[n, b*32+d] * W[d,o] ----------------
__global__ void k3(const float* __restrict__ Ysum, const float* __restrict__ W,
                   float* __restrict__ out) {
  __shared__ float yt[32][68];  // [d][n]
  __shared__ float wt[32][68];  // [d][o]
  int n0 = blockIdx.x * 64;
  int b = blockIdx.y;
  int tid = threadIdx.x;
#pragma unroll
  for (int q = 0; q < 2; q++) {
    int flat = (q * 256 + tid) * 4;
    int r = flat >> 5, c = flat & 31;
    float4 a = *(const float4*)(Ysum + (size_t)(n0 + r) * BD + b * 32 + c);
    yt[c + 0][r] = a.x; yt[c + 1][r] = a.y; yt[c + 2][r] = a.z; yt[c + 3][r] = a.w;
    int rd = flat >> 6, co = flat & 63;
    *(float4*)&wt[rd][co] = *(const float4*)(W + rd * 64 + co);
  }
  __syncthreads();
  int tx = tid & 15, ty = tid >> 4;
  float acc[4][4];
#pragma unroll
  for (int a = 0; a < 4; a++)
#pragma unroll
    for (int bq = 0; bq < 4; bq++) acc[a][bq] = 0.f;
#pragma unroll
  for (int d = 0; d < 32; d++) {
    float4 a = *(const float4*)&yt[d][ty * 4];
    float4 w4 = *(const float4*)&wt[d][tx * 4];
    float av[4] = {a.x, a.y, a.z, a.w}, wv[4] = {w4.x, w4.y, w4.z, w4.w};
#pragma unroll
    for (int nn = 0; nn < 4; nn++)
#pragma unroll
      for (int oo = 0; oo < 4; oo++) acc[nn][oo] += av[nn] * wv[oo];
  }
#pragma unroll
  for (int nn = 0; nn < 4; nn++) {
    float4 v = {acc[nn][0], acc[nn][1], acc[nn][2], acc[nn][3]};
    *(float4*)(out + (size_t)b * NN * 64 + (size_t)(n0 + ty * 4 + nn) * 64 + tx * 4) = v;
  }
}

extern "C" void kernel_launch(void* const* d_in, const int* in_sizes, int n_in,
                              void* d_out, int out_size, void* d_ws, size_t ws_size,
                              hipStream_t stream) {
  const int* erow = (const int*)d_in[0];
  const int* ecol = (const int*)d_in[1];
  const float* ew = (const float*)d_in[2];
  const float* X = (const float*)d_in[3];
  const float* Z = (const float*)d_in[4];
  const float* W = (const float*)d_in[5];
  float* out = (float*)d_out;

  char* p = (char*)d_ws;
  float* Y0 = (float*)p;                     p += (size_t)NN * BD * 4;  // 16 MB
  float* Ysum = (float*)p;                   p += (size_t)NN * BD * 4;  // 16 MB
  float* Y1 = (float*)p;                     p += (size_t)NN * BD * 4;  // 16 MB
  unsigned short* Y0bB = (unsigned short*)p; p += (size_t)BD * NN * 2;  // 8 MB
  unsigned short* Zh = (unsigned short*)p;   p += (size_t)NN * DE * 2;  // 1 MB
  unsigned short* Zl = (unsigned short*)p;   p += (size_t)NN * DE * 2;  // 1 MB
  float* ssum = (float*)p;                   p += NN * 4;
  float* invs = (float*)p;                   p += NN * 4;
  int* cnt = (int*)p;                        p += 2 * NN * 4;
  int* rowptr = (int*)p;                     p += 2 * RPS * 4;
  int* fill = (int*)p;                       p += 2 * NN * 4;
  int* ecol_s = (int*)p;                     p += (size_t)2 * NE * 4;
  float* ew_s = (float*)p;                   p += (size_t)2 * NE * 4;

  k_transpose<<<dim3(NN / 32, BD / 32), dim3(32, 8), 0, stream>>>(X, Y0, Ysum);
  k_zsplit<<<(NN * DE / 4) / 256, 256, 0, stream>>>(Z, Zh, Zl);
  hipMemsetAsync(ssum, 0, NN * sizeof(float), stream);
  hipMemsetAsync(cnt, 0, 2 * NN * sizeof(int), stream);
  k_hist<<<2 * NE / 256, 256, 0, stream>>>(erow, cnt);
  k_scan<<<2, 256, 0, stream>>>(cnt, rowptr, fill);
  k_scatter<<<2 * NE / 256, 256, 0, stream>>>(erow, ecol, ew, fill, ecol_s, ew_s);
  k_colsum<<<dim3(128, 4), 256, 0, stream>>>(Zh, Zl, ssum);
  k_inv<<<NN / 256, 256, 0, stream>>>(ssum, invs);
  for (int k = 0; k < 2; k++) {
    const int* rp = rowptr + k * RPS;
    const int* cs = ecol_s + (size_t)k * NE;
    const float* ws = ew_s + (size_t)k * NE;
    k_csr<<<NN / 4, 256, 0, stream>>>(rp, cs, ws, Y0, Y1, nullptr, 1.0f);
    k_csr<<<NN / 4, 256, 0, stream>>>(rp, cs, ws, Y1, Ysum, Y1, 2.0f);
  }
  k_castB<<<(NN * BD / 8) / 256, 256, 0, stream>>>(X, Y0bB);
  k2<<<512, 256, 0, stream>>>(Zh, Zl, Y0bB, invs, Ysum);
  k3<<<dim3(NN / 64, 16), 256, 0, stream>>>(Ysum, W, out);
}